// Round 7
// baseline (873.690 us; speedup 1.0000x reference)
//
#include <hip/hip_runtime.h>
#include <hip/hip_bf16.h>

typedef __attribute__((ext_vector_type(8))) short bf16x8;
typedef __attribute__((ext_vector_type(4))) float f32x4;
typedef unsigned short u16;

#define BATCH 12288

__device__ __forceinline__ u16 f2bf(float f){
  __hip_bfloat16 h = __float2bfloat16(f);
  return *reinterpret_cast<u16*>(&h);
}
__device__ __forceinline__ float bf2f(u16 u){
  __hip_bfloat16 h; *reinterpret_cast<u16*>(&h) = u;
  return __bfloat162float(h);
}
__device__ __forceinline__ f32x4 mfma16(bf16x8 a, bf16x8 b, f32x4 c){
  return __builtin_amdgcn_mfma_f32_16x16x32_bf16(a, b, c, 0, 0, 0);
}
__device__ __forceinline__ float softplusf(float v){ return log1pf(expf(v)); }

// 4 cumulative-threshold tests on one value: exactly 2 insts each.
// count if v <= t  (v = -0.5*d^2, t = -0.5*q^2  <=>  d^2 >= q^2, inclusive like ref)
__device__ __forceinline__ void hist4(float v, float t0, float t1, float t2, float t3,
                                      unsigned &c0, unsigned &c1, unsigned &c2, unsigned &c3){
  asm("v_cmp_ngt_f32 vcc, %4, %5\n\t"
      "v_addc_co_u32 %0, vcc, 0, %0, vcc\n\t"
      "v_cmp_ngt_f32 vcc, %4, %6\n\t"
      "v_addc_co_u32 %1, vcc, 0, %1, vcc\n\t"
      "v_cmp_ngt_f32 vcc, %4, %7\n\t"
      "v_addc_co_u32 %2, vcc, 0, %2, vcc\n\t"
      "v_cmp_ngt_f32 vcc, %4, %8\n\t"
      "v_addc_co_u32 %3, vcc, 0, %3, vcc"
      : "+v"(c0), "+v"(c1), "+v"(c2), "+v"(c3)
      : "v"(v), "v"(t0), "v"(t1), "v"(t2), "v"(t3)
      : "vcc");
}

// ---------------- K0: 8 weight matrices -> zero-padded [128][128] bf16 slabs,
// plus zero cnt[] and done[] (replaces the memset launch).
__global__ __launch_bounds__(256) void k_wconv8(
    const float* __restrict__ s0, const float* __restrict__ s1,
    const float* __restrict__ s2, const float* __restrict__ s3,
    const float* __restrict__ s4, const float* __restrict__ s5,
    const float* __restrict__ s6, const float* __restrict__ s7,
    u16* __restrict__ dst, unsigned* __restrict__ cntz)
{
  int blk = blockIdx.x;            // 512 blocks: 8 slabs x 64
  int slab = blk >> 6;
  const float* src; int rows, cols;
  switch (slab){
    case 0: src = s0; rows = 118; cols = 128; break;
    case 1: src = s1; rows = 118; cols = 128; break;
    case 2: src = s2; rows = 109; cols = 118; break;
    case 3: src = s3; rows = 109; cols = 128; break;
    case 4: src = s4; rows = 100; cols = 109; break;
    case 5: src = s5; rows = 100; cols = 128; break;
    case 6: src = s6; rows =  92; cols = 100; break;
    default: src = s7; rows =  92; cols = 128; break;
  }
  int z = blk * 256 + threadIdx.x;
  if (z < 36912) cntz[z] = 0u;                    // 12288*3 cnt + 48 done
  int idx = (blk & 63) * 256 + threadIdx.x;       // 16384 per slab
  int r = idx >> 7, c = idx & 127;
  float v = (r < rows && c < cols) ? src[r * cols + c] : 0.f;
  dst[slab * 16384 + idx] = f2bf(v);
}

// ---------------- K1: 4-layer compression MLP via MFMA (32 rows / block)
__global__ __launch_bounds__(256) void k_mlp(const float* __restrict__ x,
    const u16* __restrict__ slabs,
    const float* __restrict__ cb0, const float* __restrict__ cb1,
    const float* __restrict__ cb2, const float* __restrict__ cb3,
    const float* __restrict__ sb0, const float* __restrict__ sb1,
    const float* __restrict__ sb2, const float* __restrict__ sb3,
    float* __restrict__ comp)
{
  const int LSTR = 136;                       // LDS row stride (bf16 elems)
  __shared__ u16 xbf[32 * 136];
  __shared__ u16 act[2][32 * 136];
  int tid = threadIdx.x;
  int lane = tid & 63, w = tid >> 6;
  int fr = lane & 15, fg = lane >> 4;
  int r0 = blockIdx.x * 32;

  // stage x (f32 -> bf16) into LDS
  #pragma unroll
  for (int i = 0; i < 4; i++){
    int slot = tid + i * 256;                 // 1024 float4 slots = 32 rows * 32
    int row = slot >> 5, c4 = slot & 31;
    float4 v = *reinterpret_cast<const float4*>(&x[(r0 + row) * 128 + c4 * 4]);
    ushort4 pk;
    pk.x = f2bf(v.x); pk.y = f2bf(v.y); pk.z = f2bf(v.z); pk.w = f2bf(v.w);
    *reinterpret_cast<ushort4*>(&xbf[row * LSTR + c4 * 4]) = pk;
  }
  __syncthreads();

  // x A-fragments kept in registers for all skip GEMMs
  bf16x8 xa[2][4];
  #pragma unroll
  for (int mf = 0; mf < 2; mf++)
    #pragma unroll
    for (int kc = 0; kc < 4; kc++)
      xa[mf][kc] = *reinterpret_cast<const bf16x8*>(&xbf[(16*mf + fr) * LSTR + kc*32 + fg*8]);

  const float* cbs[4] = {cb0, cb1, cb2, cb3};
  const float* sbs[4] = {sb0, sb1, sb2, sb3};
  const int douts[4] = {118, 109, 100, 92};

  #pragma unroll
  for (int s = 0; s < 4; s++){
    const u16* aIn  = (s == 0) ? xbf : &act[(s + 1) & 1][0];
    u16*       aOut = &act[s & 1][0];
    const u16* cwS = slabs + (2*s)     * 16384;
    const u16* swS = slabs + (2*s + 1) * 16384;
    const float* cb = cbs[s];
    const float* sb = sbs[s];
    int dout = douts[s];

    bf16x8 af[2][4];
    #pragma unroll
    for (int mf = 0; mf < 2; mf++)
      #pragma unroll
      for (int kc = 0; kc < 4; kc++)
        af[mf][kc] = *reinterpret_cast<const bf16x8*>(&aIn[(16*mf + fr) * LSTR + kc*32 + fg*8]);

    f32x4 ac1[2][2], ac2[2][2];
    #pragma unroll
    for (int mf = 0; mf < 2; mf++)
      #pragma unroll
      for (int nf = 0; nf < 2; nf++){
        ac1[mf][nf] = (f32x4){0.f,0.f,0.f,0.f};
        ac2[mf][nf] = (f32x4){0.f,0.f,0.f,0.f};
      }

    #pragma unroll
    for (int nf = 0; nf < 2; nf++){
      int o = 32*w + 16*nf + fr;              // output col this lane supplies as B-row
      #pragma unroll
      for (int kc = 0; kc < 4; kc++){
        bf16x8 b1 = *reinterpret_cast<const bf16x8*>(&cwS[o * 128 + kc*32 + fg*8]);
        bf16x8 b2 = *reinterpret_cast<const bf16x8*>(&swS[o * 128 + kc*32 + fg*8]);
        ac1[0][nf] = mfma16(af[0][kc], b1, ac1[0][nf]);
        ac1[1][nf] = mfma16(af[1][kc], b1, ac1[1][nf]);
        ac2[0][nf] = mfma16(xa[0][kc], b2, ac2[0][nf]);
        ac2[1][nf] = mfma16(xa[1][kc], b2, ac2[1][nf]);
      }
    }

    #pragma unroll
    for (int nf = 0; nf < 2; nf++){
      int col = 32*w + 16*nf + fr;
      float cbv = (col < dout) ? cb[col] : 0.f;
      float sbv = (col < dout) ? sb[col] : 0.f;
      #pragma unroll
      for (int mf = 0; mf < 2; mf++){
        #pragma unroll
        for (int r = 0; r < 4; r++){
          float t1 = ac1[mf][nf][r] + cbv;
          float g = 0.5f * t1 * (1.f + erff(t1 * 0.70710678118654752f));
          float v = g + 0.1f * (ac2[mf][nf][r] + sbv);
          int row = 16*mf + fg*4 + r;
          if (s < 3){
            aOut[row * LSTR + col] = (col < dout) ? f2bf(v) : (u16)0;
          } else {
            if (col < 92) comp[(r0 + row) * 92 + col] = v;
          }
        }
      }
    }
    __syncthreads();
  }
}

// ---------------- K2a: per-row finalize: bf16 C (padded 96), -0.5*norms, energy, basin probs
__global__ __launch_bounds__(256) void k_rowfin(const float* __restrict__ comp,
    u16* __restrict__ Cbf, float* __restrict__ nrm2,
    const float* __restrict__ basin_c, const float* __restrict__ basin_d,
    const float* __restrict__ basin_w,
    float* __restrict__ energy_out, float* __restrict__ probs_out)
{
  int tid = threadIdx.x; int lane = tid & 63; int w = tid >> 6;
  int row = blockIdx.x * 4 + w;

  float c0 = comp[row * 92 + lane];
  int d2i = 64 + lane;
  float c1 = (d2i < 92) ? comp[row * 92 + d2i] : 0.f;

  u16 b0 = f2bf(c0);
  u16 b1 = (d2i < 92) ? f2bf(c1) : (u16)0;
  Cbf[row * 96 + lane] = b0;
  if (lane < 32) Cbf[row * 96 + 64 + lane] = b1;   // cols 64..95 (92..95 zero pad)

  // row norm from the *bf16* values (consistency with MFMA gram); store -0.5*|c|^2
  float f0 = bf2f(b0), f1 = bf2f(b1);
  float ns = f0*f0 + f1*f1;
  #pragma unroll
  for (int m = 1; m < 64; m <<= 1) ns += __shfl_xor(ns, m);
  if (lane == 0) nrm2[row] = -0.5f * ns;

  // basin distances (f32 compressed)
  float bd[8];
  #pragma unroll
  for (int b = 0; b < 8; b++){
    float e0 = c0 - basin_c[b * 92 + lane];
    float p = e0 * e0;
    if (d2i < 92){ float e1 = c1 - basin_c[b * 92 + d2i]; p += e1 * e1; }
    #pragma unroll
    for (int m = 1; m < 64; m <<= 1) p += __shfl_xor(p, m);
    bd[b] = sqrtf(p);
  }
  float z[8]; float mx = -1e30f;
  #pragma unroll
  for (int b = 0; b < 8; b++){
    float wd = softplusf(basin_w[b]);
    z[b] = -bd[b] / wd;
    mx = fmaxf(mx, z[b]);
  }
  float p8[8]; float ssum = 0.f;
  #pragma unroll
  for (int b = 0; b < 8; b++){ p8[b] = expf(z[b] - mx); ssum += p8[b]; }
  float inv = 1.f / ssum; float en = 0.f;
  #pragma unroll
  for (int b = 0; b < 8; b++){ p8[b] *= inv; en += p8[b] * basin_d[b]; }

  if (lane == 0) energy_out[row] = en;
  if (lane < 8){
    float v = (lane & 4) ? ((lane & 2) ? ((lane & 1) ? p8[7] : p8[6])
                                       : ((lane & 1) ? p8[5] : p8[4]))
                         : ((lane & 2) ? ((lane & 1) ? p8[3] : p8[2])
                                       : ((lane & 1) ? p8[1] : p8[0]));
    probs_out[row * 8 + lane] = v;
  }
}

// ---------------- K2b: pairwise-distance shell histogram via 16x16x32 bf16 MFMA gram.
// Round-4 numerics (f32 C-init = -0.5(|a|^2+|b|^2); D = -0.5*d^2; test D <= -q^2/2).
// 512 threads / 8 waves per block, i-tile 256 rows, j-chunk 384 staged 64 at a time.
// Last block per i-tile (completion counter) computes fused feats+occ epilogue.
__global__ __launch_bounds__(512, 8) void k_pdist(const u16* __restrict__ Cbf,
    const float* __restrict__ nrm2, const float* __restrict__ shell_bnd,
    unsigned* __restrict__ cnt, unsigned* __restrict__ done,
    const float* __restrict__ comp, const float* __restrict__ se_w,
    const float* __restrict__ se_b, float* __restrict__ feats_out,
    float* __restrict__ occ_out)
{
  __shared__ u16 Bs[2][64 * 104];   // 104-elem stride: 13x16B granules
  __shared__ float Ns[2][64];
  __shared__ unsigned lastFlag;
  int tid = threadIdx.x; int lane = tid & 63; int w = tid >> 6;   // w: 0..7
  int fr = lane & 15, fg = lane >> 4;
  int blk = blockIdx.x;
  int ib = blk % 48, jc = blk / 48;         // 48 i-tiles(256) x 32 j-chunks(384)
  int i0 = ib * 256, j0 = jc * 384;

  float q0 = softplusf(shell_bnd[0]); float mq0 = -0.5f * q0 * q0;
  float q1 = softplusf(shell_bnd[1]); float mq1 = -0.5f * q1 * q1;
  float q2 = softplusf(shell_bnd[2]); float mq2 = -0.5f * q2 * q2;
  float q3 = softplusf(shell_bnd[3]); float mq3 = -0.5f * q3 * q3;

  int wrow0 = i0 + 32 * w;
  bf16x8 A[2][3];
  #pragma unroll
  for (int mf = 0; mf < 2; mf++)
    #pragma unroll
    for (int kc = 0; kc < 3; kc++)
      A[mf][kc] = *reinterpret_cast<const bf16x8*>(&Cbf[(wrow0 + 16*mf + fr) * 96 + kc*32 + fg*8]);

  float hr[2][4];                            // -0.5*|row|^2
  #pragma unroll
  for (int mf = 0; mf < 2; mf++)
    #pragma unroll
    for (int r = 0; r < 4; r++)
      hr[mf][r] = nrm2[wrow0 + 16*mf + fg*4 + r];

  unsigned c[2][4][4];
  #pragma unroll
  for (int mf = 0; mf < 2; mf++)
    #pragma unroll
    for (int r = 0; r < 4; r++)
      #pragma unroll
      for (int t = 0; t < 4; t++) c[mf][r][t] = 0u;

  // staging offsets: 768 chunks of 16B = 64 rows x 12; 512 threads -> 1.5 chunks each
  int r0c = tid / 12,          s0c = (tid - r0c * 12) * 8;
  int ch1 = tid + 512;
  int r1c = ch1 / 12,          s1c = (ch1 - r1c * 12) * 8;
  int d0c = r0c * 104 + s0c,   d1c = r1c * 104 + s1c;
  bool has1 = (tid < 256);

  // stage step 0
  {
    *reinterpret_cast<bf16x8*>(&Bs[0][d0c]) =
      *reinterpret_cast<const bf16x8*>(&Cbf[(j0 + r0c) * 96 + s0c]);
    if (has1)
      *reinterpret_cast<bf16x8*>(&Bs[0][d1c]) =
        *reinterpret_cast<const bf16x8*>(&Cbf[(j0 + r1c) * 96 + s1c]);
    if (tid < 64) Ns[0][tid] = nrm2[j0 + tid];
  }
  __syncthreads();

  for (int s = 0; s < 6; s++){
    int p = s & 1;
    if (s < 5){
      int jr0 = j0 + (s + 1) * 64;           // stage next into p^1 (consumed last iter)
      *reinterpret_cast<bf16x8*>(&Bs[p ^ 1][d0c]) =
        *reinterpret_cast<const bf16x8*>(&Cbf[(jr0 + r0c) * 96 + s0c]);
      if (has1)
        *reinterpret_cast<bf16x8*>(&Bs[p ^ 1][d1c]) =
          *reinterpret_cast<const bf16x8*>(&Cbf[(jr0 + r1c) * 96 + s1c]);
      if (tid < 64) Ns[p ^ 1][tid] = nrm2[jr0 + tid];
    }

    #pragma unroll
    for (int nt = 0; nt < 4; nt++){
      bf16x8 B0 = *reinterpret_cast<const bf16x8*>(&Bs[p][(nt*16 + fr) * 104 + 0*32 + fg*8]);
      bf16x8 B1 = *reinterpret_cast<const bf16x8*>(&Bs[p][(nt*16 + fr) * 104 + 1*32 + fg*8]);
      bf16x8 B2 = *reinterpret_cast<const bf16x8*>(&Bs[p][(nt*16 + fr) * 104 + 2*32 + fg*8]);
      float hc = Ns[p][nt*16 + fr];

      f32x4 g0, g1;
      #pragma unroll
      for (int r = 0; r < 4; r++){ g0[r] = hr[0][r] + hc; g1[r] = hr[1][r] + hc; }
      g0 = mfma16(A[0][0], B0, g0); g0 = mfma16(A[0][1], B1, g0); g0 = mfma16(A[0][2], B2, g0);
      g1 = mfma16(A[1][0], B0, g1); g1 = mfma16(A[1][1], B1, g1); g1 = mfma16(A[1][2], B2, g1);

      #pragma unroll
      for (int r = 0; r < 4; r++)
        hist4(g0[r], mq0, mq1, mq2, mq3, c[0][r][0], c[0][r][1], c[0][r][2], c[0][r][3]);
      #pragma unroll
      for (int r = 0; r < 4; r++)
        hist4(g1[r], mq0, mq1, mq2, mq3, c[1][r][0], c[1][r][1], c[1][r][2], c[1][r][3]);
    }
    __syncthreads();
  }

  // reduce over the 16 column-lanes, then shell diffs + atomics
  #pragma unroll
  for (int mf = 0; mf < 2; mf++)
    #pragma unroll
    for (int r = 0; r < 4; r++)
      #pragma unroll
      for (int t = 0; t < 4; t++){
        int v = (int)c[mf][r][t];
        v += __shfl_xor(v, 1); v += __shfl_xor(v, 2);
        v += __shfl_xor(v, 4); v += __shfl_xor(v, 8);
        c[mf][r][t] = (unsigned)v;
      }
  if (fr == 0){
    #pragma unroll
    for (int mf = 0; mf < 2; mf++)
      #pragma unroll
      for (int r = 0; r < 4; r++){
        int row = wrow0 + 16*mf + fg*4 + r;
        #pragma unroll
        for (int t = 0; t < 3; t++){
          unsigned o = c[mf][r][t] - c[mf][r][t + 1];
          if (o) atomicAdd(&cnt[row * 3 + t], o);
        }
      }
  }

  // ---- fused feats epilogue: last j-block of this i-tile finishes the 256 rows
  __threadfence();
  __syncthreads();
  if (tid == 0){
    unsigned old = atomicAdd(&done[ib], 1u);
    lastFlag = (old == 31u) ? 1u : 0u;
  }
  __syncthreads();
  if (lastFlag){
    const float denom = 1.081f * 12287.0f + 1e-8f;
    int row = i0 + (tid >> 1);
    int half = tid & 1;
    float o0 = (float)atomicAdd(&cnt[row * 3 + 0], 0u) / denom;
    float o1 = (float)atomicAdd(&cnt[row * 3 + 1], 0u) / denom;
    float o2 = (float)atomicAdd(&cnt[row * 3 + 2], 0u) / denom;
    int dbeg = half * 46;
    #pragma unroll 2
    for (int d = dbeg; d < dbeg + 46; d++){
      float v = comp[row * 92 + d]
              + o0 * se_w[d * 3 + 0] + o1 * se_w[d * 3 + 1] + o2 * se_w[d * 3 + 2]
              + se_b[d];
      feats_out[row * 92 + d] = v;
    }
    if (!half){
      occ_out[row * 3 + 0] = o0;
      occ_out[row * 3 + 1] = o1;
      occ_out[row * 3 + 2] = o2;
    }
  }
}

extern "C" void kernel_launch(void* const* d_in, const int* in_sizes, int n_in,
                              void* d_out, int out_size, void* d_ws, size_t ws_size,
                              hipStream_t stream) {
  (void)in_sizes; (void)n_in; (void)out_size; (void)ws_size;

  const float* x = (const float*)d_in[0];
  const float* cw[4] = {(const float*)d_in[1], (const float*)d_in[5], (const float*)d_in[9],  (const float*)d_in[13]};
  const float* cb[4] = {(const float*)d_in[2], (const float*)d_in[6], (const float*)d_in[10], (const float*)d_in[14]};
  const float* sw[4] = {(const float*)d_in[3], (const float*)d_in[7], (const float*)d_in[11], (const float*)d_in[15]};
  const float* sb[4] = {(const float*)d_in[4], (const float*)d_in[8], (const float*)d_in[12], (const float*)d_in[16]};
  const float* shell_bnd = (const float*)d_in[17];
  const float* se_w = (const float*)d_in[18];
  const float* se_b = (const float*)d_in[19];
  const float* basin_c = (const float*)d_in[20];
  const float* basin_d = (const float*)d_in[21];
  const float* basin_w = (const float*)d_in[22];

  char* ws = (char*)d_ws;
  float*    comp  = (float*)(ws);                    // 12288*92*4   = 4,521,984
  u16*      Cbf   = (u16*)  (ws + 4521984);          // 12288*96*2   = 2,359,296
  float*    nrm2  = (float*)(ws + 6881280);          // 12288*4      =    49,152
  unsigned* cnt   = (unsigned*)(ws + 6930432);       // 12288*3*4    =   147,456
  unsigned* done  = (unsigned*)(ws + 7077888);       // 48*4 (contiguous after cnt)
  u16*      slabs = (u16*)  (ws + 7078144);          // 8*16384*2    =   262,144

  float* out = (float*)d_out;
  float* feats_out  = out;                 // 12288*92
  float* energy_out = out + 1130496;       // 12288
  float* probs_out  = out + 1142784;       // 12288*8
  float* occ_out    = out + 1241088;       // 12288*3

  k_wconv8<<<512, 256, 0, stream>>>(cw[0], sw[0], cw[1], sw[1], cw[2], sw[2], cw[3], sw[3],
                                    slabs, cnt);

  k_mlp<<<384, 256, 0, stream>>>(x, slabs,
      cb[0], cb[1], cb[2], cb[3], sb[0], sb[1], sb[2], sb[3], comp);

  k_rowfin<<<3072, 256, 0, stream>>>(comp, Cbf, nrm2, basin_c, basin_d, basin_w,
                                     energy_out, probs_out);

  k_pdist<<<1536, 512, 0, stream>>>(Cbf, nrm2, shell_bnd, cnt, done,
                                    comp, se_w, se_b, feats_out, occ_out);
}

// Round 9
// 376.798 us; speedup vs baseline: 2.3187x; 2.3187x over previous
//
#include <hip/hip_runtime.h>
#include <hip/hip_bf16.h>

typedef __attribute__((ext_vector_type(8))) short bf16x8;
typedef __attribute__((ext_vector_type(4))) float f32x4;
typedef unsigned short u16;

#define BATCH 12288

__device__ __forceinline__ u16 f2bf(float f){
  __hip_bfloat16 h = __float2bfloat16(f);
  return *reinterpret_cast<u16*>(&h);
}
__device__ __forceinline__ float bf2f(u16 u){
  __hip_bfloat16 h; *reinterpret_cast<u16*>(&h) = u;
  return __bfloat162float(h);
}
__device__ __forceinline__ f32x4 mfma16(bf16x8 a, bf16x8 b, f32x4 c){
  return __builtin_amdgcn_mfma_f32_16x16x32_bf16(a, b, c, 0, 0, 0);
}
__device__ __forceinline__ float softplusf(float v){ return log1pf(expf(v)); }

// ---------------- K0: all 8 weight matrices -> zero-padded [128][128] bf16 slabs
__global__ __launch_bounds__(256) void k_wconv8(
    const float* __restrict__ s0, const float* __restrict__ s1,
    const float* __restrict__ s2, const float* __restrict__ s3,
    const float* __restrict__ s4, const float* __restrict__ s5,
    const float* __restrict__ s6, const float* __restrict__ s7,
    u16* __restrict__ dst)
{
  int blk = blockIdx.x;            // 512 blocks: 8 slabs x 64
  int slab = blk >> 6;
  const float* src; int rows, cols;
  switch (slab){
    case 0: src = s0; rows = 118; cols = 128; break;
    case 1: src = s1; rows = 118; cols = 128; break;
    case 2: src = s2; rows = 109; cols = 118; break;
    case 3: src = s3; rows = 109; cols = 128; break;
    case 4: src = s4; rows = 100; cols = 109; break;
    case 5: src = s5; rows = 100; cols = 128; break;
    case 6: src = s6; rows =  92; cols = 100; break;
    default: src = s7; rows =  92; cols = 128; break;
  }
  int idx = (blk & 63) * 256 + threadIdx.x;       // 16384 per slab
  int r = idx >> 7, c = idx & 127;
  float v = (r < rows && c < cols) ? src[r * cols + c] : 0.f;
  dst[slab * 16384 + idx] = f2bf(v);
}

// ---------------- K1: 4-layer compression MLP via MFMA (32 rows / block)
__global__ __launch_bounds__(256) void k_mlp(const float* __restrict__ x,
    const u16* __restrict__ slabs,
    const float* __restrict__ cb0, const float* __restrict__ cb1,
    const float* __restrict__ cb2, const float* __restrict__ cb3,
    const float* __restrict__ sb0, const float* __restrict__ sb1,
    const float* __restrict__ sb2, const float* __restrict__ sb3,
    float* __restrict__ comp)
{
  const int LSTR = 136;                       // LDS row stride (bf16 elems)
  __shared__ u16 xbf[32 * 136];
  __shared__ u16 act[2][32 * 136];
  int tid = threadIdx.x;
  int lane = tid & 63, w = tid >> 6;
  int fr = lane & 15, fg = lane >> 4;
  int r0 = blockIdx.x * 32;

  // stage x (f32 -> bf16) into LDS
  #pragma unroll
  for (int i = 0; i < 4; i++){
    int slot = tid + i * 256;                 // 1024 float4 slots = 32 rows * 32
    int row = slot >> 5, c4 = slot & 31;
    float4 v = *reinterpret_cast<const float4*>(&x[(r0 + row) * 128 + c4 * 4]);
    ushort4 pk;
    pk.x = f2bf(v.x); pk.y = f2bf(v.y); pk.z = f2bf(v.z); pk.w = f2bf(v.w);
    *reinterpret_cast<ushort4*>(&xbf[row * LSTR + c4 * 4]) = pk;
  }
  __syncthreads();

  // x A-fragments kept in registers for all skip GEMMs
  bf16x8 xa[2][4];
  #pragma unroll
  for (int mf = 0; mf < 2; mf++)
    #pragma unroll
    for (int kc = 0; kc < 4; kc++)
      xa[mf][kc] = *reinterpret_cast<const bf16x8*>(&xbf[(16*mf + fr) * LSTR + kc*32 + fg*8]);

  const float* cbs[4] = {cb0, cb1, cb2, cb3};
  const float* sbs[4] = {sb0, sb1, sb2, sb3};
  const int douts[4] = {118, 109, 100, 92};

  #pragma unroll
  for (int s = 0; s < 4; s++){
    const u16* aIn  = (s == 0) ? xbf : &act[(s + 1) & 1][0];
    u16*       aOut = &act[s & 1][0];
    const u16* cwS = slabs + (2*s)     * 16384;
    const u16* swS = slabs + (2*s + 1) * 16384;
    const float* cb = cbs[s];
    const float* sb = sbs[s];
    int dout = douts[s];

    bf16x8 af[2][4];
    #pragma unroll
    for (int mf = 0; mf < 2; mf++)
      #pragma unroll
      for (int kc = 0; kc < 4; kc++)
        af[mf][kc] = *reinterpret_cast<const bf16x8*>(&aIn[(16*mf + fr) * LSTR + kc*32 + fg*8]);

    f32x4 ac1[2][2], ac2[2][2];
    #pragma unroll
    for (int mf = 0; mf < 2; mf++)
      #pragma unroll
      for (int nf = 0; nf < 2; nf++){
        ac1[mf][nf] = (f32x4){0.f,0.f,0.f,0.f};
        ac2[mf][nf] = (f32x4){0.f,0.f,0.f,0.f};
      }

    #pragma unroll
    for (int nf = 0; nf < 2; nf++){
      int o = 32*w + 16*nf + fr;              // output col this lane supplies as B-row
      #pragma unroll
      for (int kc = 0; kc < 4; kc++){
        bf16x8 b1 = *reinterpret_cast<const bf16x8*>(&cwS[o * 128 + kc*32 + fg*8]);
        bf16x8 b2 = *reinterpret_cast<const bf16x8*>(&swS[o * 128 + kc*32 + fg*8]);
        ac1[0][nf] = mfma16(af[0][kc], b1, ac1[0][nf]);
        ac1[1][nf] = mfma16(af[1][kc], b1, ac1[1][nf]);
        ac2[0][nf] = mfma16(xa[0][kc], b2, ac2[0][nf]);
        ac2[1][nf] = mfma16(xa[1][kc], b2, ac2[1][nf]);
      }
    }

    #pragma unroll
    for (int nf = 0; nf < 2; nf++){
      int col = 32*w + 16*nf + fr;
      float cbv = (col < dout) ? cb[col] : 0.f;
      float sbv = (col < dout) ? sb[col] : 0.f;
      #pragma unroll
      for (int mf = 0; mf < 2; mf++){
        #pragma unroll
        for (int r = 0; r < 4; r++){
          float t1 = ac1[mf][nf][r] + cbv;
          float g = 0.5f * t1 * (1.f + erff(t1 * 0.70710678118654752f));
          float v = g + 0.1f * (ac2[mf][nf][r] + sbv);
          int row = 16*mf + fg*4 + r;
          if (s < 3){
            aOut[row * LSTR + col] = (col < dout) ? f2bf(v) : (u16)0;
          } else {
            if (col < 92) comp[(r0 + row) * 92 + col] = v;
          }
        }
      }
    }
    __syncthreads();
  }
}

// ---------------- K2a: per-row finalize: bf16 C (padded 96), -0.5*norms, energy, basin probs
__global__ __launch_bounds__(256) void k_rowfin(const float* __restrict__ comp,
    u16* __restrict__ Cbf, float* __restrict__ nrm2,
    const float* __restrict__ basin_c, const float* __restrict__ basin_d,
    const float* __restrict__ basin_w,
    float* __restrict__ energy_out, float* __restrict__ probs_out)
{
  int tid = threadIdx.x; int lane = tid & 63; int w = tid >> 6;
  int row = blockIdx.x * 4 + w;

  float c0 = comp[row * 92 + lane];
  int d2i = 64 + lane;
  float c1 = (d2i < 92) ? comp[row * 92 + d2i] : 0.f;

  u16 b0 = f2bf(c0);
  u16 b1 = (d2i < 92) ? f2bf(c1) : (u16)0;
  Cbf[row * 96 + lane] = b0;
  if (lane < 32) Cbf[row * 96 + 64 + lane] = b1;   // cols 64..95 (92..95 zero pad)

  // row norm from the *bf16* values (consistency with MFMA gram); store -0.5*|c|^2
  float f0 = bf2f(b0), f1 = bf2f(b1);
  float ns = f0*f0 + f1*f1;
  #pragma unroll
  for (int m = 1; m < 64; m <<= 1) ns += __shfl_xor(ns, m);
  if (lane == 0) nrm2[row] = -0.5f * ns;

  // basin distances (f32 compressed)
  float bd[8];
  #pragma unroll
  for (int b = 0; b < 8; b++){
    float e0 = c0 - basin_c[b * 92 + lane];
    float p = e0 * e0;
    if (d2i < 92){ float e1 = c1 - basin_c[b * 92 + d2i]; p += e1 * e1; }
    #pragma unroll
    for (int m = 1; m < 64; m <<= 1) p += __shfl_xor(p, m);
    bd[b] = sqrtf(p);
  }
  float z[8]; float mx = -1e30f;
  #pragma unroll
  for (int b = 0; b < 8; b++){
    float wd = softplusf(basin_w[b]);
    z[b] = -bd[b] / wd;
    mx = fmaxf(mx, z[b]);
  }
  float p8[8]; float ssum = 0.f;
  #pragma unroll
  for (int b = 0; b < 8; b++){ p8[b] = expf(z[b] - mx); ssum += p8[b]; }
  float inv = 1.f / ssum; float en = 0.f;
  #pragma unroll
  for (int b = 0; b < 8; b++){ p8[b] *= inv; en += p8[b] * basin_d[b]; }

  if (lane == 0) energy_out[row] = en;
  if (lane < 8){
    float v = (lane & 4) ? ((lane & 2) ? ((lane & 1) ? p8[7] : p8[6])
                                       : ((lane & 1) ? p8[5] : p8[4]))
                         : ((lane & 2) ? ((lane & 1) ? p8[3] : p8[2])
                                       : ((lane & 1) ? p8[1] : p8[0]));
    probs_out[row * 8 + lane] = v;
  }
}

// ---------------- K2b: SYMMETRIC pairwise-distance shell histogram (16x16x32 MFMA gram).
// Round-4 numerics: f32 C-init -0.5(|a|^2+|b|^2); D = -0.5*d^2; test D <= -q^2/2.
// Triangular tile grid: 128x128 tiles, (ib <= jb), 96*97/2 = 4656 blocks.
// Each pair counted once; increments row-counter (i side) AND column-counter (j side).
// Diagonal blocks mask i >= j elements (v := 1.0f fails every negative threshold).
__global__ __launch_bounds__(256, 4) void k_pdist(const u16* __restrict__ Cbf,
    const float* __restrict__ nrm2, const float* __restrict__ shell_bnd,
    unsigned* __restrict__ cnt)
{
  __shared__ u16 Bs[128 * 104];   // 104-elem stride: 13x16B granules
  __shared__ float Ns[128];
  int tid = threadIdx.x; int lane = tid & 63; int w = tid >> 6;
  int fr = lane & 15, fg = lane >> 4;

  // triangular decode: rows a and 95-a of the (i<=j) triangle together have 97 entries
  int bid = blockIdx.x;
  int a = bid / 97, b = bid - a * 97;
  int ib, jb;
  if (b < 96 - a){ ib = a;      jb = a + b; }
  else           { ib = 95 - a; jb = 95 - a + (b - (96 - a)); }
  int i0 = ib * 128, j0 = jb * 128;
  bool diag = (ib == jb);

  float q0 = softplusf(shell_bnd[0]); float mq0 = -0.5f * q0 * q0;
  float q1 = softplusf(shell_bnd[1]); float mq1 = -0.5f * q1 * q1;
  float q2 = softplusf(shell_bnd[2]); float mq2 = -0.5f * q2 * q2;
  float q3 = softplusf(shell_bnd[3]); float mq3 = -0.5f * q3 * q3;

  int wrow0 = i0 + 32 * w;
  bf16x8 A[2][3];
  #pragma unroll
  for (int mf = 0; mf < 2; mf++)
    #pragma unroll
    for (int kc = 0; kc < 3; kc++)
      A[mf][kc] = *reinterpret_cast<const bf16x8*>(&Cbf[(wrow0 + 16*mf + fr) * 96 + kc*32 + fg*8]);

  float hr[2][4];                            // -0.5*|row|^2
  #pragma unroll
  for (int mf = 0; mf < 2; mf++)
    #pragma unroll
    for (int r = 0; r < 4; r++)
      hr[mf][r] = nrm2[wrow0 + 16*mf + fg*4 + r];

  unsigned c[2][4][4];
  #pragma unroll
  for (int mf = 0; mf < 2; mf++)
    #pragma unroll
    for (int r = 0; r < 4; r++)
      #pragma unroll
      for (int t = 0; t < 4; t++) c[mf][r][t] = 0u;

  // stage the full 128-row j-tile once: 1536 chunks of 16B = 128 rows x 12
  #pragma unroll
  for (int t = 0; t < 6; t++){
    int ch = tid + t * 256;
    int rr = ch / 12, sl = ch - rr * 12;
    *reinterpret_cast<bf16x8*>(&Bs[rr * 104 + sl * 8]) =
      *reinterpret_cast<const bf16x8*>(&Cbf[(j0 + rr) * 96 + sl * 8]);
  }
  if (tid < 128) Ns[tid] = nrm2[j0 + tid];
  __syncthreads();

  #pragma unroll
  for (int nt = 0; nt < 8; nt++){
    bf16x8 B0 = *reinterpret_cast<const bf16x8*>(&Bs[(nt*16 + fr) * 104 + 0*32 + fg*8]);
    bf16x8 B1 = *reinterpret_cast<const bf16x8*>(&Bs[(nt*16 + fr) * 104 + 1*32 + fg*8]);
    bf16x8 B2 = *reinterpret_cast<const bf16x8*>(&Bs[(nt*16 + fr) * 104 + 2*32 + fg*8]);
    float hc = Ns[nt*16 + fr];
    int jcol = j0 + nt*16 + fr;

    f32x4 g0, g1;
    #pragma unroll
    for (int r = 0; r < 4; r++){ g0[r] = hr[0][r] + hc; g1[r] = hr[1][r] + hc; }
    g0 = mfma16(A[0][0], B0, g0); g0 = mfma16(A[0][1], B1, g0); g0 = mfma16(A[0][2], B2, g0);
    g1 = mfma16(A[1][0], B0, g1); g1 = mfma16(A[1][1], B1, g1); g1 = mfma16(A[1][2], B2, g1);

    unsigned cc0 = 0, cc1 = 0, cc2 = 0, cc3 = 0;   // column counters (this nt)
    #pragma unroll
    for (int mf = 0; mf < 2; mf++)
      #pragma unroll
      for (int r = 0; r < 4; r++){
        float v = (mf == 0) ? g0[r] : g1[r];
        if (diag){
          int irow = wrow0 + 16*mf + fg*4 + r;
          v = (irow < jcol) ? v : 1.0f;            // excludes i>=j (and self-pairs)
        }
        unsigned h0 = (v <= mq0) ? 1u : 0u;
        unsigned h1 = (v <= mq1) ? 1u : 0u;
        unsigned h2 = (v <= mq2) ? 1u : 0u;
        unsigned h3 = (v <= mq3) ? 1u : 0u;
        c[mf][r][0] += h0; c[mf][r][1] += h1; c[mf][r][2] += h2; c[mf][r][3] += h3;
        cc0 += h0; cc1 += h1; cc2 += h2; cc3 += h3;
      }

    // column reduce across the 4 fg groups (lanes l, l^16, l^32, l^48)
    cc0 += __shfl_xor(cc0, 16); cc0 += __shfl_xor(cc0, 32);
    cc1 += __shfl_xor(cc1, 16); cc1 += __shfl_xor(cc1, 32);
    cc2 += __shfl_xor(cc2, 16); cc2 += __shfl_xor(cc2, 32);
    cc3 += __shfl_xor(cc3, 16); cc3 += __shfl_xor(cc3, 32);
    if (fg == 0){
      unsigned o0 = cc0 - cc1, o1 = cc1 - cc2, o2 = cc2 - cc3;
      if (o0) atomicAdd(&cnt[jcol * 3 + 0], o0);
      if (o1) atomicAdd(&cnt[jcol * 3 + 1], o1);
      if (o2) atomicAdd(&cnt[jcol * 3 + 2], o2);
    }
  }

  // row reduce over the 16 column-lanes, then shell diffs + atomics
  #pragma unroll
  for (int mf = 0; mf < 2; mf++)
    #pragma unroll
    for (int r = 0; r < 4; r++)
      #pragma unroll
      for (int t = 0; t < 4; t++){
        int v = (int)c[mf][r][t];
        v += __shfl_xor(v, 1); v += __shfl_xor(v, 2);
        v += __shfl_xor(v, 4); v += __shfl_xor(v, 8);
        c[mf][r][t] = (unsigned)v;
      }
  if (fr == 0){
    #pragma unroll
    for (int mf = 0; mf < 2; mf++)
      #pragma unroll
      for (int r = 0; r < 4; r++){
        int row = wrow0 + 16*mf + fg*4 + r;
        #pragma unroll
        for (int t = 0; t < 3; t++){
          unsigned o = c[mf][r][t] - c[mf][r][t + 1];
          if (o) atomicAdd(&cnt[row * 3 + t], o);
        }
      }
  }
}

// ---------------- K3: feats = comp + occ @ se_w^T + se_b ; occ output
__global__ __launch_bounds__(256) void k_feats(const float* __restrict__ comp,
    const unsigned* __restrict__ cnt, const float* __restrict__ se_w,
    const float* __restrict__ se_b, float* __restrict__ feats_out,
    float* __restrict__ occ_out)
{
  int tid = threadIdx.x; int lane = tid & 63; int w = tid >> 6;
  int row = blockIdx.x * 4 + w;
  const float denom = 1.081f * 12287.0f + 1e-8f;

  float o0 = (float)cnt[row * 3 + 0] / denom;
  float o1 = (float)cnt[row * 3 + 1] / denom;
  float o2 = (float)cnt[row * 3 + 2] / denom;

  {
    int d = lane;
    float v = comp[row * 92 + d]
            + o0 * se_w[d * 3 + 0] + o1 * se_w[d * 3 + 1] + o2 * se_w[d * 3 + 2]
            + se_b[d];
    feats_out[row * 92 + d] = v;
  }
  int d2 = lane + 64;
  if (d2 < 92){
    float v = comp[row * 92 + d2]
            + o0 * se_w[d2 * 3 + 0] + o1 * se_w[d2 * 3 + 1] + o2 * se_w[d2 * 3 + 2]
            + se_b[d2];
    feats_out[row * 92 + d2] = v;
  }
  if (lane < 3){
    float ov = (lane == 0) ? o0 : ((lane == 1) ? o1 : o2);
    occ_out[row * 3 + lane] = ov;
  }
}

extern "C" void kernel_launch(void* const* d_in, const int* in_sizes, int n_in,
                              void* d_out, int out_size, void* d_ws, size_t ws_size,
                              hipStream_t stream) {
  (void)in_sizes; (void)n_in; (void)out_size; (void)ws_size;

  const float* x = (const float*)d_in[0];
  const float* cw[4] = {(const float*)d_in[1], (const float*)d_in[5], (const float*)d_in[9],  (const float*)d_in[13]};
  const float* cb[4] = {(const float*)d_in[2], (const float*)d_in[6], (const float*)d_in[10], (const float*)d_in[14]};
  const float* sw[4] = {(const float*)d_in[3], (const float*)d_in[7], (const float*)d_in[11], (const float*)d_in[15]};
  const float* sb[4] = {(const float*)d_in[4], (const float*)d_in[8], (const float*)d_in[12], (const float*)d_in[16]};
  const float* shell_bnd = (const float*)d_in[17];
  const float* se_w = (const float*)d_in[18];
  const float* se_b = (const float*)d_in[19];
  const float* basin_c = (const float*)d_in[20];
  const float* basin_d = (const float*)d_in[21];
  const float* basin_w = (const float*)d_in[22];

  char* ws = (char*)d_ws;
  float*    comp  = (float*)(ws);                    // 12288*92*4   = 4,521,984
  u16*      Cbf   = (u16*)  (ws + 4521984);          // 12288*96*2   = 2,359,296
  float*    nrm2  = (float*)(ws + 6881280);          // 12288*4      =    49,152
  unsigned* cnt   = (unsigned*)(ws + 6930432);       // 12288*3*4    =   147,456
  u16*      slabs = (u16*)  (ws + 7077888);          // 8*16384*2    =   262,144

  float* out = (float*)d_out;
  float* feats_out  = out;                 // 12288*92
  float* energy_out = out + 1130496;       // 12288
  float* probs_out  = out + 1142784;       // 12288*8
  float* occ_out    = out + 1241088;       // 12288*3

  hipMemsetAsync(cnt, 0, 147456, stream);

  k_wconv8<<<512, 256, 0, stream>>>(cw[0], sw[0], cw[1], sw[1], cw[2], sw[2], cw[3], sw[3],
                                    slabs);

  k_mlp<<<384, 256, 0, stream>>>(x, slabs,
      cb[0], cb[1], cb[2], cb[3], sb[0], sb[1], sb[2], sb[3], comp);

  k_rowfin<<<3072, 256, 0, stream>>>(comp, Cbf, nrm2, basin_c, basin_d, basin_w,
                                     energy_out, probs_out);

  k_pdist<<<4656, 256, 0, stream>>>(Cbf, nrm2, shell_bnd, cnt);

  k_feats<<<3072, 256, 0, stream>>>(comp, cnt, se_w, se_b, feats_out, occ_out);
}

// Round 10
// 298.569 us; speedup vs baseline: 2.9263x; 1.2620x over previous
//
#include <hip/hip_runtime.h>
#include <hip/hip_bf16.h>

typedef __attribute__((ext_vector_type(8))) short bf16x8;
typedef __attribute__((ext_vector_type(4))) float f32x4;
typedef unsigned short u16;

#define BATCH 12288

__device__ __forceinline__ u16 f2bf(float f){
  __hip_bfloat16 h = __float2bfloat16(f);
  return *reinterpret_cast<u16*>(&h);
}
__device__ __forceinline__ float bf2f(u16 u){
  __hip_bfloat16 h; *reinterpret_cast<u16*>(&h) = u;
  return __bfloat162float(h);
}
__device__ __forceinline__ f32x4 mfma16(bf16x8 a, bf16x8 b, f32x4 c){
  return __builtin_amdgcn_mfma_f32_16x16x32_bf16(a, b, c, 0, 0, 0);
}
__device__ __forceinline__ float softplusf(float v){ return log1pf(expf(v)); }

// ---------------- K0: all 8 weight matrices -> zero-padded [128][128] bf16 slabs
__global__ __launch_bounds__(256) void k_wconv8(
    const float* __restrict__ s0, const float* __restrict__ s1,
    const float* __restrict__ s2, const float* __restrict__ s3,
    const float* __restrict__ s4, const float* __restrict__ s5,
    const float* __restrict__ s6, const float* __restrict__ s7,
    u16* __restrict__ dst)
{
  int blk = blockIdx.x;            // 512 blocks: 8 slabs x 64
  int slab = blk >> 6;
  const float* src; int rows, cols;
  switch (slab){
    case 0: src = s0; rows = 118; cols = 128; break;
    case 1: src = s1; rows = 118; cols = 128; break;
    case 2: src = s2; rows = 109; cols = 118; break;
    case 3: src = s3; rows = 109; cols = 128; break;
    case 4: src = s4; rows = 100; cols = 109; break;
    case 5: src = s5; rows = 100; cols = 128; break;
    case 6: src = s6; rows =  92; cols = 100; break;
    default: src = s7; rows =  92; cols = 128; break;
  }
  int idx = (blk & 63) * 256 + threadIdx.x;       // 16384 per slab
  int r = idx >> 7, c = idx & 127;
  float v = (r < rows && c < cols) ? src[r * cols + c] : 0.f;
  dst[slab * 16384 + idx] = f2bf(v);
}

// ---------------- K1: 4-layer compression MLP via MFMA (32 rows / block)
__global__ __launch_bounds__(256) void k_mlp(const float* __restrict__ x,
    const u16* __restrict__ slabs,
    const float* __restrict__ cb0, const float* __restrict__ cb1,
    const float* __restrict__ cb2, const float* __restrict__ cb3,
    const float* __restrict__ sb0, const float* __restrict__ sb1,
    const float* __restrict__ sb2, const float* __restrict__ sb3,
    float* __restrict__ comp)
{
  const int LSTR = 136;                       // LDS row stride (bf16 elems)
  __shared__ u16 xbf[32 * 136];
  __shared__ u16 act[2][32 * 136];
  int tid = threadIdx.x;
  int lane = tid & 63, w = tid >> 6;
  int fr = lane & 15, fg = lane >> 4;
  int r0 = blockIdx.x * 32;

  // stage x (f32 -> bf16) into LDS
  #pragma unroll
  for (int i = 0; i < 4; i++){
    int slot = tid + i * 256;                 // 1024 float4 slots = 32 rows * 32
    int row = slot >> 5, c4 = slot & 31;
    float4 v = *reinterpret_cast<const float4*>(&x[(r0 + row) * 128 + c4 * 4]);
    ushort4 pk;
    pk.x = f2bf(v.x); pk.y = f2bf(v.y); pk.z = f2bf(v.z); pk.w = f2bf(v.w);
    *reinterpret_cast<ushort4*>(&xbf[row * LSTR + c4 * 4]) = pk;
  }
  __syncthreads();

  // x A-fragments kept in registers for all skip GEMMs
  bf16x8 xa[2][4];
  #pragma unroll
  for (int mf = 0; mf < 2; mf++)
    #pragma unroll
    for (int kc = 0; kc < 4; kc++)
      xa[mf][kc] = *reinterpret_cast<const bf16x8*>(&xbf[(16*mf + fr) * LSTR + kc*32 + fg*8]);

  const float* cbs[4] = {cb0, cb1, cb2, cb3};
  const float* sbs[4] = {sb0, sb1, sb2, sb3};
  const int douts[4] = {118, 109, 100, 92};

  #pragma unroll
  for (int s = 0; s < 4; s++){
    const u16* aIn  = (s == 0) ? xbf : &act[(s + 1) & 1][0];
    u16*       aOut = &act[s & 1][0];
    const u16* cwS = slabs + (2*s)     * 16384;
    const u16* swS = slabs + (2*s + 1) * 16384;
    const float* cb = cbs[s];
    const float* sb = sbs[s];
    int dout = douts[s];

    bf16x8 af[2][4];
    #pragma unroll
    for (int mf = 0; mf < 2; mf++)
      #pragma unroll
      for (int kc = 0; kc < 4; kc++)
        af[mf][kc] = *reinterpret_cast<const bf16x8*>(&aIn[(16*mf + fr) * LSTR + kc*32 + fg*8]);

    f32x4 ac1[2][2], ac2[2][2];
    #pragma unroll
    for (int mf = 0; mf < 2; mf++)
      #pragma unroll
      for (int nf = 0; nf < 2; nf++){
        ac1[mf][nf] = (f32x4){0.f,0.f,0.f,0.f};
        ac2[mf][nf] = (f32x4){0.f,0.f,0.f,0.f};
      }

    #pragma unroll
    for (int nf = 0; nf < 2; nf++){
      int o = 32*w + 16*nf + fr;              // output col this lane supplies as B-row
      #pragma unroll
      for (int kc = 0; kc < 4; kc++){
        bf16x8 b1 = *reinterpret_cast<const bf16x8*>(&cwS[o * 128 + kc*32 + fg*8]);
        bf16x8 b2 = *reinterpret_cast<const bf16x8*>(&swS[o * 128 + kc*32 + fg*8]);
        ac1[0][nf] = mfma16(af[0][kc], b1, ac1[0][nf]);
        ac1[1][nf] = mfma16(af[1][kc], b1, ac1[1][nf]);
        ac2[0][nf] = mfma16(xa[0][kc], b2, ac2[0][nf]);
        ac2[1][nf] = mfma16(xa[1][kc], b2, ac2[1][nf]);
      }
    }

    #pragma unroll
    for (int nf = 0; nf < 2; nf++){
      int col = 32*w + 16*nf + fr;
      float cbv = (col < dout) ? cb[col] : 0.f;
      float sbv = (col < dout) ? sb[col] : 0.f;
      #pragma unroll
      for (int mf = 0; mf < 2; mf++){
        #pragma unroll
        for (int r = 0; r < 4; r++){
          float t1 = ac1[mf][nf][r] + cbv;
          float g = 0.5f * t1 * (1.f + erff(t1 * 0.70710678118654752f));
          float v = g + 0.1f * (ac2[mf][nf][r] + sbv);
          int row = 16*mf + fg*4 + r;
          if (s < 3){
            aOut[row * LSTR + col] = (col < dout) ? f2bf(v) : (u16)0;
          } else {
            if (col < 92) comp[(r0 + row) * 92 + col] = v;
          }
        }
      }
    }
    __syncthreads();
  }
}

// ---------------- K2a: per-row finalize: bf16 C (padded 96), -0.5*norms, energy, basin probs
__global__ __launch_bounds__(256) void k_rowfin(const float* __restrict__ comp,
    u16* __restrict__ Cbf, float* __restrict__ nrm2,
    const float* __restrict__ basin_c, const float* __restrict__ basin_d,
    const float* __restrict__ basin_w,
    float* __restrict__ energy_out, float* __restrict__ probs_out)
{
  int tid = threadIdx.x; int lane = tid & 63; int w = tid >> 6;
  int row = blockIdx.x * 4 + w;

  float c0 = comp[row * 92 + lane];
  int d2i = 64 + lane;
  float c1 = (d2i < 92) ? comp[row * 92 + d2i] : 0.f;

  u16 b0 = f2bf(c0);
  u16 b1 = (d2i < 92) ? f2bf(c1) : (u16)0;
  Cbf[row * 96 + lane] = b0;
  if (lane < 32) Cbf[row * 96 + 64 + lane] = b1;   // cols 64..95 (92..95 zero pad)

  // row norm from the *bf16* values (consistency with MFMA gram); store -0.5*|c|^2
  float f0 = bf2f(b0), f1 = bf2f(b1);
  float ns = f0*f0 + f1*f1;
  #pragma unroll
  for (int m = 1; m < 64; m <<= 1) ns += __shfl_xor(ns, m);
  if (lane == 0) nrm2[row] = -0.5f * ns;

  // basin distances (f32 compressed)
  float bd[8];
  #pragma unroll
  for (int b = 0; b < 8; b++){
    float e0 = c0 - basin_c[b * 92 + lane];
    float p = e0 * e0;
    if (d2i < 92){ float e1 = c1 - basin_c[b * 92 + d2i]; p += e1 * e1; }
    #pragma unroll
    for (int m = 1; m < 64; m <<= 1) p += __shfl_xor(p, m);
    bd[b] = sqrtf(p);
  }
  float z[8]; float mx = -1e30f;
  #pragma unroll
  for (int b = 0; b < 8; b++){
    float wd = softplusf(basin_w[b]);
    z[b] = -bd[b] / wd;
    mx = fmaxf(mx, z[b]);
  }
  float p8[8]; float ssum = 0.f;
  #pragma unroll
  for (int b = 0; b < 8; b++){ p8[b] = expf(z[b] - mx); ssum += p8[b]; }
  float inv = 1.f / ssum; float en = 0.f;
  #pragma unroll
  for (int b = 0; b < 8; b++){ p8[b] *= inv; en += p8[b] * basin_d[b]; }

  if (lane == 0) energy_out[row] = en;
  if (lane < 8){
    float v = (lane & 4) ? ((lane & 2) ? ((lane & 1) ? p8[7] : p8[6])
                                       : ((lane & 1) ? p8[5] : p8[4]))
                         : ((lane & 2) ? ((lane & 1) ? p8[3] : p8[2])
                                       : ((lane & 1) ? p8[1] : p8[0]));
    probs_out[row * 8 + lane] = v;
  }
}

// ---------------- K2b: SYMMETRIC pairwise-distance shell histogram (16x16x32 MFMA gram).
// Round-4 numerics: f32 C-init -0.5(|a|^2+|b|^2); D = -0.5*d^2; test D <= -q^2/2.
// Triangular tile grid: 128x128 tiles, (ib <= jb), 96*97/2 = 4656 blocks.
// Column-side counts accumulate in LDS (per-wave slices); global atomics ONCE per
// block (round-9's per-nt contended atomics caused 767 MB of HBM write traffic).
__global__ __launch_bounds__(256, 4) void k_pdist(const u16* __restrict__ Cbf,
    const float* __restrict__ nrm2, const float* __restrict__ shell_bnd,
    unsigned* __restrict__ cnt)
{
  __shared__ u16 Bs[128 * 104];       // 26.0 KB: 13x16B granules per row
  __shared__ float Ns[128];
  __shared__ unsigned colc[4][128][4]; // 8 KB: per-wave column counters
  int tid = threadIdx.x; int lane = tid & 63; int w = tid >> 6;
  int fr = lane & 15, fg = lane >> 4;

  // triangular decode: rows a and 95-a of the (i<=j) triangle together have 97 entries
  int bid = blockIdx.x;
  int a = bid / 97, b = bid - a * 97;
  int ib, jb;
  if (b < 96 - a){ ib = a;      jb = a + b; }
  else           { ib = 95 - a; jb = 95 - a + (b - (96 - a)); }
  int i0 = ib * 128, j0 = jb * 128;
  bool diag = (ib == jb);

  float q0 = softplusf(shell_bnd[0]); float mq0 = -0.5f * q0 * q0;
  float q1 = softplusf(shell_bnd[1]); float mq1 = -0.5f * q1 * q1;
  float q2 = softplusf(shell_bnd[2]); float mq2 = -0.5f * q2 * q2;
  float q3 = softplusf(shell_bnd[3]); float mq3 = -0.5f * q3 * q3;

  int wrow0 = i0 + 32 * w;
  bf16x8 A[2][3];
  #pragma unroll
  for (int mf = 0; mf < 2; mf++)
    #pragma unroll
    for (int kc = 0; kc < 3; kc++)
      A[mf][kc] = *reinterpret_cast<const bf16x8*>(&Cbf[(wrow0 + 16*mf + fr) * 96 + kc*32 + fg*8]);

  float hr[2][4];                            // -0.5*|row|^2
  #pragma unroll
  for (int mf = 0; mf < 2; mf++)
    #pragma unroll
    for (int r = 0; r < 4; r++)
      hr[mf][r] = nrm2[wrow0 + 16*mf + fg*4 + r];

  unsigned c[2][4][4];
  #pragma unroll
  for (int mf = 0; mf < 2; mf++)
    #pragma unroll
    for (int r = 0; r < 4; r++)
      #pragma unroll
      for (int t = 0; t < 4; t++) c[mf][r][t] = 0u;

  // zero the column-counter LDS
  {
    unsigned* cz = &colc[0][0][0];
    #pragma unroll
    for (int i = 0; i < 8; i++) cz[tid + i * 256] = 0u;
  }

  // stage the full 128-row j-tile once: 1536 chunks of 16B = 128 rows x 12
  #pragma unroll
  for (int t = 0; t < 6; t++){
    int ch = tid + t * 256;
    int rr = ch / 12, sl = ch - rr * 12;
    *reinterpret_cast<bf16x8*>(&Bs[rr * 104 + sl * 8]) =
      *reinterpret_cast<const bf16x8*>(&Cbf[(j0 + rr) * 96 + sl * 8]);
  }
  if (tid < 128) Ns[tid] = nrm2[j0 + tid];
  __syncthreads();

  #pragma unroll
  for (int nt = 0; nt < 8; nt++){
    bf16x8 B0 = *reinterpret_cast<const bf16x8*>(&Bs[(nt*16 + fr) * 104 + 0*32 + fg*8]);
    bf16x8 B1 = *reinterpret_cast<const bf16x8*>(&Bs[(nt*16 + fr) * 104 + 1*32 + fg*8]);
    bf16x8 B2 = *reinterpret_cast<const bf16x8*>(&Bs[(nt*16 + fr) * 104 + 2*32 + fg*8]);
    float hc = Ns[nt*16 + fr];
    int jcol = j0 + nt*16 + fr;

    f32x4 g0, g1;
    #pragma unroll
    for (int r = 0; r < 4; r++){ g0[r] = hr[0][r] + hc; g1[r] = hr[1][r] + hc; }
    g0 = mfma16(A[0][0], B0, g0); g0 = mfma16(A[0][1], B1, g0); g0 = mfma16(A[0][2], B2, g0);
    g1 = mfma16(A[1][0], B0, g1); g1 = mfma16(A[1][1], B1, g1); g1 = mfma16(A[1][2], B2, g1);

    unsigned cc0 = 0, cc1 = 0, cc2 = 0, cc3 = 0;   // column counters (this nt)
    #pragma unroll
    for (int mf = 0; mf < 2; mf++)
      #pragma unroll
      for (int r = 0; r < 4; r++){
        float v = (mf == 0) ? g0[r] : g1[r];
        if (diag){
          int irow = wrow0 + 16*mf + fg*4 + r;
          v = (irow < jcol) ? v : 1.0f;            // excludes i>=j (and self-pairs)
        }
        unsigned h0 = (v <= mq0) ? 1u : 0u;
        unsigned h1 = (v <= mq1) ? 1u : 0u;
        unsigned h2 = (v <= mq2) ? 1u : 0u;
        unsigned h3 = (v <= mq3) ? 1u : 0u;
        c[mf][r][0] += h0; c[mf][r][1] += h1; c[mf][r][2] += h2; c[mf][r][3] += h3;
        cc0 += h0; cc1 += h1; cc2 += h2; cc3 += h3;
      }

    // column reduce across the 4 fg groups (lanes l, l^16, l^32, l^48)
    cc0 += __shfl_xor(cc0, 16); cc0 += __shfl_xor(cc0, 32);
    cc1 += __shfl_xor(cc1, 16); cc1 += __shfl_xor(cc1, 32);
    cc2 += __shfl_xor(cc2, 16); cc2 += __shfl_xor(cc2, 32);
    cc3 += __shfl_xor(cc3, 16); cc3 += __shfl_xor(cc3, 32);
    if (fg == 0){                     // each wave owns slice [w]; lane fr unique -> no race
      int col = nt*16 + fr;
      colc[w][col][0] += cc0;
      colc[w][col][1] += cc1;
      colc[w][col][2] += cc2;
      colc[w][col][3] += cc3;
    }
  }

  // row reduce over the 16 column-lanes, then shell diffs + atomics
  #pragma unroll
  for (int mf = 0; mf < 2; mf++)
    #pragma unroll
    for (int r = 0; r < 4; r++)
      #pragma unroll
      for (int t = 0; t < 4; t++){
        int v = (int)c[mf][r][t];
        v += __shfl_xor(v, 1); v += __shfl_xor(v, 2);
        v += __shfl_xor(v, 4); v += __shfl_xor(v, 8);
        c[mf][r][t] = (unsigned)v;
      }
  if (fr == 0){
    #pragma unroll
    for (int mf = 0; mf < 2; mf++)
      #pragma unroll
      for (int r = 0; r < 4; r++){
        int row = wrow0 + 16*mf + fg*4 + r;
        #pragma unroll
        for (int t = 0; t < 3; t++){
          unsigned o = c[mf][r][t] - c[mf][r][t + 1];
          if (o) atomicAdd(&cnt[row * 3 + t], o);
        }
      }
  }

  // column-side: reduce the 4 wave slices, one atomic set per column per block
  __syncthreads();
  if (tid < 128){
    unsigned s0 = colc[0][tid][0] + colc[1][tid][0] + colc[2][tid][0] + colc[3][tid][0];
    unsigned s1 = colc[0][tid][1] + colc[1][tid][1] + colc[2][tid][1] + colc[3][tid][1];
    unsigned s2 = colc[0][tid][2] + colc[1][tid][2] + colc[2][tid][2] + colc[3][tid][2];
    unsigned s3 = colc[0][tid][3] + colc[1][tid][3] + colc[2][tid][3] + colc[3][tid][3];
    unsigned o0 = s0 - s1, o1 = s1 - s2, o2 = s2 - s3;
    int jcol = j0 + tid;
    if (o0) atomicAdd(&cnt[jcol * 3 + 0], o0);
    if (o1) atomicAdd(&cnt[jcol * 3 + 1], o1);
    if (o2) atomicAdd(&cnt[jcol * 3 + 2], o2);
  }
}

// ---------------- K3: feats = comp + occ @ se_w^T + se_b ; occ output
__global__ __launch_bounds__(256) void k_feats(const float* __restrict__ comp,
    const unsigned* __restrict__ cnt, const float* __restrict__ se_w,
    const float* __restrict__ se_b, float* __restrict__ feats_out,
    float* __restrict__ occ_out)
{
  int tid = threadIdx.x; int lane = tid & 63; int w = tid >> 6;
  int row = blockIdx.x * 4 + w;
  const float denom = 1.081f * 12287.0f + 1e-8f;

  float o0 = (float)cnt[row * 3 + 0] / denom;
  float o1 = (float)cnt[row * 3 + 1] / denom;
  float o2 = (float)cnt[row * 3 + 2] / denom;

  {
    int d = lane;
    float v = comp[row * 92 + d]
            + o0 * se_w[d * 3 + 0] + o1 * se_w[d * 3 + 1] + o2 * se_w[d * 3 + 2]
            + se_b[d];
    feats_out[row * 92 + d] = v;
  }
  int d2 = lane + 64;
  if (d2 < 92){
    float v = comp[row * 92 + d2]
            + o0 * se_w[d2 * 3 + 0] + o1 * se_w[d2 * 3 + 1] + o2 * se_w[d2 * 3 + 2]
            + se_b[d2];
    feats_out[row * 92 + d2] = v;
  }
  if (lane < 3){
    float ov = (lane == 0) ? o0 : ((lane == 1) ? o1 : o2);
    occ_out[row * 3 + lane] = ov;
  }
}

extern "C" void kernel_launch(void* const* d_in, const int* in_sizes, int n_in,
                              void* d_out, int out_size, void* d_ws, size_t ws_size,
                              hipStream_t stream) {
  (void)in_sizes; (void)n_in; (void)out_size; (void)ws_size;

  const float* x = (const float*)d_in[0];
  const float* cw[4] = {(const float*)d_in[1], (const float*)d_in[5], (const float*)d_in[9],  (const float*)d_in[13]};
  const float* cb[4] = {(const float*)d_in[2], (const float*)d_in[6], (const float*)d_in[10], (const float*)d_in[14]};
  const float* sw[4] = {(const float*)d_in[3], (const float*)d_in[7], (const float*)d_in[11], (const float*)d_in[15]};
  const float* sb[4] = {(const float*)d_in[4], (const float*)d_in[8], (const float*)d_in[12], (const float*)d_in[16]};
  const float* shell_bnd = (const float*)d_in[17];
  const float* se_w = (const float*)d_in[18];
  const float* se_b = (const float*)d_in[19];
  const float* basin_c = (const float*)d_in[20];
  const float* basin_d = (const float*)d_in[21];
  const float* basin_w = (const float*)d_in[22];

  char* ws = (char*)d_ws;
  float*    comp  = (float*)(ws);                    // 12288*92*4   = 4,521,984
  u16*      Cbf   = (u16*)  (ws + 4521984);          // 12288*96*2   = 2,359,296
  float*    nrm2  = (float*)(ws + 6881280);          // 12288*4      =    49,152
  unsigned* cnt   = (unsigned*)(ws + 6930432);       // 12288*3*4    =   147,456
  u16*      slabs = (u16*)  (ws + 7077888);          // 8*16384*2    =   262,144

  float* out = (float*)d_out;
  float* feats_out  = out;                 // 12288*92
  float* energy_out = out + 1130496;       // 12288
  float* probs_out  = out + 1142784;       // 12288*8
  float* occ_out    = out + 1241088;       // 12288*3

  hipMemsetAsync(cnt, 0, 147456, stream);

  k_wconv8<<<512, 256, 0, stream>>>(cw[0], sw[0], cw[1], sw[1], cw[2], sw[2], cw[3], sw[3],
                                    slabs);

  k_mlp<<<384, 256, 0, stream>>>(x, slabs,
      cb[0], cb[1], cb[2], cb[3], sb[0], sb[1], sb[2], sb[3], comp);

  k_rowfin<<<3072, 256, 0, stream>>>(comp, Cbf, nrm2, basin_c, basin_d, basin_w,
                                     energy_out, probs_out);

  k_pdist<<<4656, 256, 0, stream>>>(Cbf, nrm2, shell_bnd, cnt);

  k_feats<<<3072, 256, 0, stream>>>(comp, cnt, se_w, se_b, feats_out, occ_out);
}